// Round 9
// baseline (209.122 us; speedup 1.0000x reference)
//
#include <hip/hip_runtime.h>

#define NN 10000
#define EE 160000
#define ETOT (EE + NN)
#define EMB 768
#define ODIM 1024
#define NEG 0.2f
#define CAP 56          // max in/out degree ~45 (Binom(160k,1e-4) max + self-loop)

// ---- workspace layout (4B units) ----
#define OFF_PT     0          // 12288 : P transposed [j*768+k] (src j<8, dst j>=8)
#define OFF_Q      12288      // 8
#define OFF_EAACC  12296      // 1 (zeroed)
#define OFF_CNTD   12304      // int[10000] (zeroed)
#define OFF_CNTS   22304      // int[10000] (zeroed)
#define ZERO_START 12296
#define ZERO_CNT   20008
#define OFF_A      32304      // 10000*16 : a_src(0..7), a_dst(8..15)
#define OFF_EDD    192304     // int2[10000*CAP] : (e, src) per dst-bucket slot
#define OFF_EDS    1312304    // int2[10000*CAP] : (e, dst) per src-bucket slot
#define OFF_RDEN   2432304    // 80000 : 1/denominator per (dst,h)
#define OFF_Z      2512304    // 2*8*768
#define OFF_YPART  2524592    // 313*6144 : y partials [b][h*768+col]
// end 4447664 floats = 17.8 MB

// K1F: PT/Q precontract + edge_attr sum + bucket fill + bias-out init
__global__ __launch_bounds__(256) void k1f(
    const float* __restrict__ W, const float* __restrict__ att_src,
    const float* __restrict__ att_dst, const float* __restrict__ W_edge,
    const float* __restrict__ att_edge, const float* __restrict__ edge_attr,
    const int* __restrict__ ei, const float* __restrict__ bias,
    const float* __restrict__ clf_W, const float* __restrict__ clf_b,
    float* __restrict__ out, float* __restrict__ ws) {
  __shared__ float red[8];
  int b = blockIdx.x;
  int* wsI = (int*)ws;
  if (b < 48) {
    int tid = b * 256 + threadIdx.x;   // 0..12287
    int k = tid >> 4, j = tid & 15, h = j & 7;
    const float* att = (j < 8) ? att_src : att_dst;
    const float* wp = W + k * ODIM + h * 128;
    const float* ap = att + h * 128;
    float acc = 0.f;
    #pragma unroll 8
    for (int c = 0; c < 128; ++c) acc += wp[c] * ap[c];
    ws[OFF_PT + j * 768 + k] = acc;    // transposed for kAx
  } else if (b == 48) {
    if (threadIdx.x < 8) {
      int h = threadIdx.x;
      float acc = 0.f;
      #pragma unroll 8
      for (int c = 0; c < 128; ++c) acc += W_edge[h * 128 + c] * att_edge[h * 128 + c];
      ws[OFF_Q + h] = acc;
    }
  } else if (b < 113) {
    int bi = b - 49;   // 64 blocks: sum edge_attr
    float acc = 0.f;
    for (int i = bi * 256 + threadIdx.x; i < EE; i += 64 * 256) acc += edge_attr[i];
    #pragma unroll
    for (int off = 32; off > 0; off >>= 1) acc += __shfl_down(acc, off, 64);
    if ((threadIdx.x & 63) == 0) atomicAdd(&ws[OFF_EAACC], acc);
  } else if (b < 778) {
    int e = (b - 113) * 256 + threadIdx.x;
    if (e >= ETOT) return;
    int src, dst;
    if (e < EE) { src = ei[e]; dst = ei[EE + e]; } else { src = dst = e - EE; }
    int pd = atomicAdd(&wsI[OFF_CNTD + dst], 1);
    if (pd < CAP) ((int2*)(wsI + OFF_EDD))[dst * CAP + pd] = make_int2(e, src);
    int ps = atomicAdd(&wsI[OFF_CNTS + src], 1);
    if (ps < CAP) ((int2*)(wsI + OFF_EDS))[src * CAP + ps] = make_int2(e, dst);
  } else {
    // out = clf_b + sum_i bias[i&1023]*clf_W[i]  (k8 atomicAdds on top)
    int t = threadIdx.x;
    float b0 = 0.f, b1 = 0.f;
    for (int i = t; i < 3072; i += 256) {
      float f = bias[i & 1023];
      b0 += f * clf_W[2 * i];
      b1 += f * clf_W[2 * i + 1];
    }
    #pragma unroll
    for (int o = 32; o > 0; o >>= 1) {
      b0 += __shfl_down(b0, o, 64);
      b1 += __shfl_down(b1, o, 64);
    }
    if ((t & 63) == 0) { red[(t >> 6) * 2] = b0; red[(t >> 6) * 2 + 1] = b1; }
    __syncthreads();
    if (t == 0) {
      out[0] = clf_b[0] + red[0] + red[2] + red[4] + red[6];
      out[1] = clf_b[1] + red[1] + red[3] + red[5] + red[7];
    }
  }
}

// KAX: A = x @ P via PT in 48KB LDS; 16 nodes/block
__global__ __launch_bounds__(256) void kAx(const float* __restrict__ x,
                                           float* __restrict__ ws) {
  __shared__ float sm[12288];
  for (int i = threadIdx.x; i < 3072; i += 256)
    ((float4*)sm)[i] = ((const float4*)(ws + OFF_PT))[i];
  __syncthreads();
  int li = threadIdx.x & 15, nl = threadIdx.x >> 4;
  int n = blockIdx.x * 16 + nl;      // 625*16 = 10000 exact
  float a[16];
  #pragma unroll
  for (int j = 0; j < 16; ++j) a[j] = 0.f;
  const float4* xr = (const float4*)(x + n * EMB);
  const float4* pT4 = (const float4*)sm;   // [j*192 + k4]
  for (int i = 0; i < 12; ++i) {
    float4 xv = xr[li + i * 16];
    int k4 = li + i * 16;
    #pragma unroll
    for (int j = 0; j < 16; ++j) {
      float4 p = pT4[j * 192 + k4];
      a[j] += xv.x * p.x + xv.y * p.y + xv.z * p.z + xv.w * p.w;
    }
  }
  __syncthreads();   // PT reads done; reuse sm for partials
  #pragma unroll
  for (int j = 0; j < 16; ++j) sm[threadIdx.x * 17 + j] = a[j];
  __syncthreads();
  int rn = threadIdx.x >> 4, rj = threadIdx.x & 15;
  float s = 0.f;
  #pragma unroll
  for (int c = 0; c < 16; ++c) s += sm[(rn * 16 + c) * 17 + rj];
  ws[OFF_A + (blockIdx.x * 16 + rn) * 16 + rj] = s;
}

// KD2: rden per (dst,h): gather (e,src) from EDD, recompute exp, sum
__global__ __launch_bounds__(128) void kD2(const float* __restrict__ edge_attr,
                                           float* __restrict__ ws) {
  int t = blockIdx.x * 128 + threadIdx.x;   // 625*128 = 80000 exact
  int dst = t >> 3, h = t & 7;
  const int* wsI = (const int*)ws;
  int deg = wsI[OFF_CNTD + dst]; if (deg > CAP) deg = CAP;
  const int2* edd = (const int2*)(wsI + OFF_EDD) + dst * CAP;
  float q = ws[OFF_Q + h];
  float adst = ws[OFF_A + dst * 16 + 8 + h];
  float eamean = ws[OFF_EAACC] * (1.0f / EE);
  float den = 0.f;
  for (int j = 0; j < deg; ++j) {
    int2 ed = edd[j];
    float ea = (ed.x < EE) ? edge_attr[ed.x] : eamean;
    float v = ws[OFF_A + ed.y * 16 + h] + adst + ea * q;
    v = (v >= 0.f) ? v : NEG * v;
    den += __expf(v);
  }
  ws[OFF_RDEN + t] = 1.0f / den;
}

// K7SZ: blocks 0..312: inline s-compute (32 nodes) + y-partials;
//       blocks 313..318: z for text/image (2 targets x 3 col-chunks)
__global__ __launch_bounds__(256) void k7sz(const float* __restrict__ x,
                                            const int* __restrict__ ei,
                                            const float* __restrict__ edge_attr,
                                            const int* __restrict__ tptr,
                                            const int* __restrict__ iptr,
                                            float* __restrict__ ws) {
  __shared__ float sm[512];
  const int* wsI = (const int*)ws;
  const int t = threadIdx.x;
  if (blockIdx.x < 313) {
    int base = blockIdx.x * 32;
    int nl = t >> 3, h = t & 7;
    int n = base + nl;
    float s = 0.f;
    if (n < NN) {
      int deg = wsI[OFF_CNTS + n]; if (deg > CAP) deg = CAP;
      const int2* eds = (const int2*)(wsI + OFF_EDS) + n * CAP;
      float q = ws[OFF_Q + h];
      float asrc = ws[OFF_A + n * 16 + h];
      float eamean = ws[OFF_EAACC] * (1.0f / EE);
      for (int j = 0; j < deg; ++j) {
        int2 ed = eds[j];
        float ea = (ed.x < EE) ? edge_attr[ed.x] : eamean;
        float v = asrc + ws[OFF_A + ed.y * 16 + 8 + h] + ea * q;
        v = (v >= 0.f) ? v : NEG * v;
        s += __expf(v) * ws[OFF_RDEN + ed.y * 8 + h];
      }
    }
    sm[t] = s;          // sm[nl*8+h]
    __syncthreads();
    float acc[3][8];
    #pragma unroll
    for (int c = 0; c < 3; ++c)
      #pragma unroll
      for (int h2 = 0; h2 < 8; ++h2) acc[c][h2] = 0.f;
    int nmax = NN - base; if (nmax > 32) nmax = 32;
    for (int i = 0; i < nmax; ++i) {
      const float* xr = x + (base + i) * EMB;
      float x0 = xr[t], x1 = xr[t + 256], x2 = xr[t + 512];
      const float* sv = &sm[i * 8];
      #pragma unroll
      for (int h2 = 0; h2 < 8; ++h2) {
        acc[0][h2] += x0 * sv[h2];
        acc[1][h2] += x1 * sv[h2];
        acc[2][h2] += x2 * sv[h2];
      }
    }
    float* yp = ws + OFF_YPART + blockIdx.x * 6144;
    #pragma unroll
    for (int h2 = 0; h2 < 8; ++h2) {
      yp[h2 * 768 + t] = acc[0][h2];
      yp[h2 * 768 + 256 + t] = acc[1][h2];
      yp[h2 * 768 + 512 + t] = acc[2][h2];
    }
  } else {
    float* wL = sm;                 // [448]
    int* srcS = (int*)(sm + 448);   // [56]
    int r = blockIdx.x - 313;       // 0..5
    int d = r / 3, kc = r % 3;      // d: 0=text 1=image; kc: 256-col chunk
    int target = (d == 0) ? tptr[0] : iptr[0];
    int deg = wsI[OFF_CNTD + target]; if (deg > CAP) deg = CAP;
    float eamean = ws[OFF_EAACC] * (1.0f / EE);
    for (int idx = t; idx < deg * 8; idx += 256) {
      int j = idx >> 3, h = idx & 7;
      int2 ed = ((const int2*)(wsI + OFF_EDD))[target * CAP + j];
      float ea = (ed.x < EE) ? edge_attr[ed.x] : eamean;
      float v = ws[OFF_A + ed.y * 16 + h] + ws[OFF_A + target * 16 + 8 + h]
              + ea * ws[OFF_Q + h];
      v = (v >= 0.f) ? v : NEG * v;
      wL[idx] = __expf(v) * ws[OFF_RDEN + target * 8 + h];
      if (h == 0) srcS[j] = ed.y;
    }
    __syncthreads();
    int col = kc * 256 + t;
    float acc[8];
    #pragma unroll
    for (int h = 0; h < 8; ++h) acc[h] = 0.f;
    for (int j = 0; j < deg; ++j) {
      float xv = x[srcS[j] * EMB + col];
      const float* wv = &wL[j * 8];
      #pragma unroll
      for (int h = 0; h < 8; ++h) acc[h] += wv[h] * xv;
    }
    #pragma unroll
    for (int h = 0; h < 8; ++h) ws[OFF_Z + (d * 8 + h) * EMB + col] = acc[h];
  }
}

// K8: Y-reduce (313 partials) + projection + classifier dot -> atomicAdd out
__global__ __launch_bounds__(128) void k8(const float* __restrict__ W,
                                          const float* __restrict__ clf_W,
                                          float* __restrict__ out,
                                          float* __restrict__ ws) {
  __shared__ float yred[384];
  __shared__ float vL[144];
  __shared__ float red[4];
  int h = blockIdx.x, kc = blockIdx.y, kbase = kc * 48;
  for (int i = threadIdx.x; i < 384; i += 128) {
    int k = i % 48, g = i / 48;     // 8 groups
    float a = 0.f;
    for (int b = g; b < 313; b += 8)
      a += ws[OFF_YPART + b * 6144 + h * 768 + kbase + k];
    yred[i] = a;
  }
  for (int i = threadIdx.x; i < 96; i += 128) {
    int d = i / 48, k = i - d * 48;
    vL[48 + i] = ws[OFF_Z + (d * 8 + h) * EMB + kbase + k];
  }
  __syncthreads();
  if (threadIdx.x < 48) {
    float a = 0.f;
    #pragma unroll
    for (int g = 0; g < 8; ++g) a += yred[g * 48 + threadIdx.x];
    vL[threadIdx.x] = a * (1.0f / NN);
  }
  __syncthreads();
  int c = threadIdx.x;
  float a0 = 0.f, a1 = 0.f, a2 = 0.f;
  #pragma unroll 4
  for (int k = 0; k < 48; ++k) {
    float wv = W[(kbase + k) * ODIM + h * 128 + c];
    a0 += vL[k] * wv;
    a1 += vL[48 + k] * wv;
    a2 += vL[96 + k] * wv;
  }
  int ib = h * 128 + c;
  float l0 = a0 * clf_W[2 * ib] + a1 * clf_W[2 * (1024 + ib)]
           + a2 * clf_W[2 * (2048 + ib)];
  float l1 = a0 * clf_W[2 * ib + 1] + a1 * clf_W[2 * (1024 + ib) + 1]
           + a2 * clf_W[2 * (2048 + ib) + 1];
  #pragma unroll
  for (int o = 32; o > 0; o >>= 1) {
    l0 += __shfl_down(l0, o, 64);
    l1 += __shfl_down(l1, o, 64);
  }
  if ((threadIdx.x & 63) == 0) {
    red[(threadIdx.x >> 6) * 2] = l0;
    red[(threadIdx.x >> 6) * 2 + 1] = l1;
  }
  __syncthreads();
  if (threadIdx.x == 0) {
    atomicAdd(&out[0], red[0] + red[2]);
    atomicAdd(&out[1], red[1] + red[3]);
  }
}

extern "C" void kernel_launch(void* const* d_in, const int* in_sizes, int n_in,
                              void* d_out, int out_size, void* d_ws, size_t ws_size,
                              hipStream_t stream) {
  const float* x        = (const float*)d_in[0];
  const int*   ei       = (const int*)d_in[1];
  const float* edge_attr= (const float*)d_in[2];
  const int*   tptr     = (const int*)d_in[3];
  const int*   iptr     = (const int*)d_in[4];
  const float* W        = (const float*)d_in[5];
  const float* att_src  = (const float*)d_in[6];
  const float* att_dst  = (const float*)d_in[7];
  const float* W_edge   = (const float*)d_in[8];
  const float* att_edge = (const float*)d_in[9];
  const float* bias     = (const float*)d_in[10];
  const float* clf_W    = (const float*)d_in[11];
  const float* clf_b    = (const float*)d_in[12];
  float* ws  = (float*)d_ws;
  float* out = (float*)d_out;

  hipMemsetAsync(ws + ZERO_START, 0, ZERO_CNT * sizeof(float), stream);
  k1f<<<779, 256, 0, stream>>>(W, att_src, att_dst, W_edge, att_edge, edge_attr,
                               ei, bias, clf_W, clf_b, out, ws);
  kAx<<<625, 256, 0, stream>>>(x, ws);
  kD2<<<625, 128, 0, stream>>>(edge_attr, ws);
  k7sz<<<319, 256, 0, stream>>>(x, ei, edge_attr, tptr, iptr, ws);
  dim3 g8(8, 16);
  k8<<<g8, 128, 0, stream>>>(W, clf_W, out, ws);
}

// Round 10
// 194.640 us; speedup vs baseline: 1.0744x; 1.0744x over previous
//
#include <hip/hip_runtime.h>

#define NN 10000
#define EE 160000
#define ETOT (EE + NN)
#define EMB 768
#define ODIM 1024
#define NEG 0.2f
#define CAP 56          // max in/out degree ~45 (Binom(160k,1e-4) max + self-loop)

// ---- workspace layout (4B units) ----
#define OFF_P      0          // 12288 : P precontract [k*16+j] (src j<8, dst j>=8)
#define OFF_Q      12288      // 8
#define OFF_EAACC  12296      // 1 (zeroed)
#define OFF_CNTD   12304      // int[10000] (zeroed)
#define OFF_CNTS   22304      // int[10000] (zeroed)
#define ZERO_START 12296
#define ZERO_CNT   20008
#define OFF_A      32304      // 10000*16 : a_src(0..7), a_dst(8..15)
#define OFF_SRCD   192304     // int[10000*CAP] : src per dst-bucket slot
#define OFF_DSTS   752304     // int[10000*CAP] : dst per src-bucket slot
#define OFF_PACK   1312304    // int[170000] : pd | ps<<16
#define OFF_EXD    1482304    // 10000*CAP*8 : exp vals, dst-major
#define OFF_EXS    5962304    // 10000*CAP*8 : exp vals, src-major
#define OFF_RDEN   10442304   // 80000 : 1/denominator per (dst,h)
#define OFF_S      10522304   // 80000 : outgoing attention sums
#define OFF_Z      10602304   // 2*8*768
#define OFF_YPART  10614592   // 157*6144 : y partials [b][h*768+col]
// end 11579200 floats = 46.3 MB

// K1F: P/Q precontract (W read ONCE: both src+dst dots per thread) +
//      edge_attr sum + bucket fill (block roles)
__global__ __launch_bounds__(256) void k1f(
    const float* __restrict__ W, const float* __restrict__ att_src,
    const float* __restrict__ att_dst, const float* __restrict__ W_edge,
    const float* __restrict__ att_edge, const float* __restrict__ edge_attr,
    const int* __restrict__ ei, float* __restrict__ ws) {
  int b = blockIdx.x;
  if (b < 24) {
    int tid = b * 256 + threadIdx.x;   // 0..6143 = (k,h) pairs
    int k = tid >> 3, h = tid & 7;
    const float* wp = W + k * ODIM + h * 128;
    const float* as = att_src + h * 128;
    const float* ad = att_dst + h * 128;
    float acc_s = 0.f, acc_d = 0.f;
    #pragma unroll 8
    for (int c = 0; c < 128; ++c) {
      float wv = wp[c];
      acc_s += wv * as[c];
      acc_d += wv * ad[c];
    }
    ws[OFF_P + k * 16 + h] = acc_s;
    ws[OFF_P + k * 16 + 8 + h] = acc_d;
  } else if (b == 24) {
    if (threadIdx.x < 8) {
      int h = threadIdx.x;
      float acc = 0.f;
      #pragma unroll 8
      for (int c = 0; c < 128; ++c) acc += W_edge[h * 128 + c] * att_edge[h * 128 + c];
      ws[OFF_Q + h] = acc;
    }
  } else if (b < 89) {
    int bi = b - 25;   // 64 blocks: sum edge_attr
    float acc = 0.f;
    for (int i = bi * 256 + threadIdx.x; i < EE; i += 64 * 256) acc += edge_attr[i];
    #pragma unroll
    for (int off = 32; off > 0; off >>= 1) acc += __shfl_down(acc, off, 64);
    if ((threadIdx.x & 63) == 0) atomicAdd(&ws[OFF_EAACC], acc);
  } else {
    int e = (b - 89) * 256 + threadIdx.x;
    if (e >= ETOT) return;
    int src, dst;
    if (e < EE) { src = ei[e]; dst = ei[EE + e]; } else { src = dst = e - EE; }
    int* cntd = (int*)(ws + OFF_CNTD);
    int* cnts = (int*)(ws + OFF_CNTS);
    int pd = atomicAdd(&cntd[dst], 1);
    if (pd < CAP) ((int*)(ws + OFF_SRCD))[dst * CAP + pd] = src;
    int ps = atomicAdd(&cnts[src], 1);
    if (ps < CAP) ((int*)(ws + OFF_DSTS))[src * CAP + ps] = dst;
    if (pd > CAP) pd = CAP;
    if (ps > CAP) ps = CAP;
    ((int*)(ws + OFF_PACK))[e] = pd | (ps << 16);
  }
}

// KAX: A = x @ P, full P in 48KB LDS (3 blocks/CU), in-LDS reduction
__global__ __launch_bounds__(256) void kAx(const float* __restrict__ x,
                                           float* __restrict__ ws) {
  __shared__ float smem[12288];
  for (int i = threadIdx.x; i < 3072; i += 256)
    ((float4*)smem)[i] = ((const float4*)(ws + OFF_P))[i];
  __syncthreads();
  int nl = threadIdx.x & 31, cg = threadIdx.x >> 5;   // cg in [0,8): 96-col group
  int n = blockIdx.x * 32 + nl;
  float a[16];
  #pragma unroll
  for (int j = 0; j < 16; ++j) a[j] = 0.f;
  if (n < NN) {
    const float4* xr = (const float4*)(x + n * EMB + cg * 96);
    for (int kk = 0; kk < 24; ++kk) {
      float4 xv = xr[kk];
      const float* pr = &smem[(cg * 96 + kk * 4) * 16];
      #pragma unroll
      for (int j = 0; j < 16; ++j) a[j] += xv.x * pr[j];
      #pragma unroll
      for (int j = 0; j < 16; ++j) a[j] += xv.y * pr[16 + j];
      #pragma unroll
      for (int j = 0; j < 16; ++j) a[j] += xv.z * pr[32 + j];
      #pragma unroll
      for (int j = 0; j < 16; ++j) a[j] += xv.w * pr[48 + j];
    }
  }
  __syncthreads();   // all P reads done; reuse smem for partials
  #pragma unroll
  for (int j = 0; j < 16; ++j) smem[(cg * 16 + j) * 33 + nl] = a[j];
  __syncthreads();
  for (int w = threadIdx.x; w < 512; w += 256) {
    int rnl = w >> 4, j = w & 15;
    int nn = blockIdx.x * 32 + rnl;
    if (nn < NN) {
      float s = 0.f;
      #pragma unroll
      for (int c2 = 0; c2 < 8; ++c2) s += smem[(c2 * 16 + j) * 33 + rnl];
      ws[OFF_A + nn * 16 + j] = s;
    }
  }
}

// KE: edge-parallel exp -> EXD/EXS; last block: bias-dot init of out
__global__ __launch_bounds__(128) void kE(const int* __restrict__ ei,
                                          const float* __restrict__ edge_attr,
                                          const float* __restrict__ bias,
                                          const float* __restrict__ clf_W,
                                          const float* __restrict__ clf_b,
                                          float* __restrict__ out,
                                          float* __restrict__ ws) {
  __shared__ float red[4];
  int* wsI = (int*)ws;
  if (blockIdx.x < 1329) {
    int e = blockIdx.x * 128 + threadIdx.x;
    if (e >= ETOT) return;
    int src, dst; float ea;
    if (e < EE) { src = ei[e]; dst = ei[EE + e]; ea = edge_attr[e]; }
    else { src = dst = e - EE; ea = ws[OFF_EAACC] * (1.0f / EE); }
    int pk = wsI[OFF_PACK + e];
    int pd = pk & 0xffff, ps = pk >> 16;
    const float4* as4 = (const float4*)(ws + OFF_A + src * 16);
    const float4* ad4 = (const float4*)(ws + OFF_A + dst * 16 + 8);
    float4 s0 = as4[0], s1 = as4[1], d0 = ad4[0], d1 = ad4[1];
    float asr[8] = {s0.x, s0.y, s0.z, s0.w, s1.x, s1.y, s1.z, s1.w};
    float ads[8] = {d0.x, d0.y, d0.z, d0.w, d1.x, d1.y, d1.z, d1.w};
    float ex[8];
    #pragma unroll
    for (int h = 0; h < 8; ++h) {
      float v = asr[h] + ads[h] + ea * ws[OFF_Q + h];
      v = (v >= 0.f) ? v : NEG * v;
      ex[h] = __expf(v);
    }
    float4 e0 = make_float4(ex[0], ex[1], ex[2], ex[3]);
    float4 e1 = make_float4(ex[4], ex[5], ex[6], ex[7]);
    if (pd < CAP) {
      float4* p = (float4*)(ws + OFF_EXD + (dst * CAP + pd) * 8);
      p[0] = e0; p[1] = e1;
    }
    if (ps < CAP) {
      float4* p = (float4*)(ws + OFF_EXS + (src * CAP + ps) * 8);
      p[0] = e0; p[1] = e1;
    }
  } else {
    // bias contribution: out = clf_b + sum_i bias[i&1023]*clf_W[i]
    int t = threadIdx.x;
    float b0 = 0.f, b1 = 0.f;
    for (int i = t; i < 3072; i += 128) {
      float f = bias[i & 1023];
      b0 += f * clf_W[2 * i];
      b1 += f * clf_W[2 * i + 1];
    }
    #pragma unroll
    for (int o = 32; o > 0; o >>= 1) {
      b0 += __shfl_down(b0, o, 64);
      b1 += __shfl_down(b1, o, 64);
    }
    if ((t & 63) == 0) { red[(t >> 6) * 2] = b0; red[(t >> 6) * 2 + 1] = b1; }
    __syncthreads();
    if (t == 0) {
      out[0] = clf_b[0] + red[0] + red[2];
      out[1] = clf_b[1] + red[1] + red[3];
    }
  }
}

// KD: rden per (dst,h) from contiguous EXD rows
__global__ __launch_bounds__(128) void kD(float* __restrict__ ws) {
  int t = blockIdx.x * 128 + threadIdx.x;   // 0..79999
  int dst = t >> 3, h = t & 7;
  int deg = ((const int*)(ws + OFF_CNTD))[dst];
  if (deg > CAP) deg = CAP;
  const float* base = ws + OFF_EXD + dst * (CAP * 8) + h;
  float den = 0.f;
  for (int j = 0; j < deg; ++j) den += base[j * 8];
  ws[OFF_RDEN + t] = 1.0f / den;
}

// KSZ: blocks 0..624: s per (src,h); blocks 625..636: z for text/image
__global__ __launch_bounds__(128) void kSZ(const float* __restrict__ x,
                                           const int* __restrict__ tptr,
                                           const int* __restrict__ iptr,
                                           float* __restrict__ ws) {
  __shared__ float sm[512];
  if (blockIdx.x < 625) {
    int t = blockIdx.x * 128 + threadIdx.x;  // 0..79999
    int src = t >> 3, h = t & 7;
    int deg = ((const int*)(ws + OFF_CNTS))[src];
    if (deg > CAP) deg = CAP;
    const int* dstrow = (const int*)(ws + OFF_DSTS) + src * CAP;
    const float* exrow = ws + OFF_EXS + src * (CAP * 8) + h;
    float s = 0.f;
    for (int j = 0; j < deg; ++j)
      s += exrow[j * 8] * ws[OFF_RDEN + dstrow[j] * 8 + h];
    ws[OFF_S + t] = s;
  } else {
    float* wL = sm;                 // [448]
    int* srcS = (int*)(sm + 448);   // [56]
    int* degP = (int*)(sm + 508);
    int r = blockIdx.x - 625;       // 0..11
    int d = r / 6, kc = r % 6;      // d: 0=text 1=image; kc: 128-col chunk
    int target = (d == 0) ? tptr[0] : iptr[0];
    if (threadIdx.x == 0) {
      int dg = ((const int*)(ws + OFF_CNTD))[target];
      degP[0] = (dg > CAP) ? CAP : dg;
    }
    __syncthreads();
    int deg = degP[0];
    for (int idx = threadIdx.x; idx < deg * 8; idx += 128) {
      int j = idx >> 3, h = idx & 7;
      wL[idx] = ws[OFF_EXD + (target * CAP + j) * 8 + h]
              * ws[OFF_RDEN + target * 8 + h];
      if (h == 0) srcS[j] = ((const int*)(ws + OFF_SRCD))[target * CAP + j];
    }
    __syncthreads();
    int col = kc * 128 + threadIdx.x;
    float acc[8];
    #pragma unroll
    for (int h = 0; h < 8; ++h) acc[h] = 0.f;
    for (int j = 0; j < deg; ++j) {
      float xv = x[srcS[j] * EMB + col];
      const float* wv = &wL[j * 8];
      #pragma unroll
      for (int h = 0; h < 8; ++h) acc[h] += wv[h] * xv;
    }
    #pragma unroll
    for (int h = 0; h < 8; ++h) ws[OFF_Z + (d * 8 + h) * EMB + col] = acc[h];
  }
}

// K7S: y-partials: YPART[bx][h*768 + col] = sum over 64 nodes of s[n][h]*x[n][col]
__global__ __launch_bounds__(256) void k7s(const float* __restrict__ x,
                                           float* __restrict__ ws) {
  __shared__ float sL[64 * 8];
  int base = blockIdx.x * 64;
  int c = blockIdx.y;
  for (int i = threadIdx.x; i < 512; i += 256) {
    int n = base + (i >> 3);
    sL[i] = (n < NN) ? ws[OFF_S + base * 8 + i] : 0.f;
  }
  __syncthreads();
  int col = c * 256 + threadIdx.x;
  float acc[8];
  #pragma unroll
  for (int h = 0; h < 8; ++h) acc[h] = 0.f;
  int nmax = (NN - base < 64) ? (NN - base) : 64;
  for (int i = 0; i < nmax; ++i) {
    float xv = x[(base + i) * EMB + col];
    const float* sv = &sL[i * 8];
    #pragma unroll
    for (int h = 0; h < 8; ++h) acc[h] += xv * sv[h];
  }
  float* yp = ws + OFF_YPART + blockIdx.x * 6144 + col;
  #pragma unroll
  for (int h = 0; h < 8; ++h) yp[h * 768] = acc[h];
}

// K8: Y-reduce + projection + classifier dot -> atomicAdd into out
__global__ __launch_bounds__(128) void k8(const float* __restrict__ W,
                                          const float* __restrict__ clf_W,
                                          float* __restrict__ out,
                                          float* __restrict__ ws) {
  __shared__ float vL[144];
  __shared__ float red[4];
  int h = blockIdx.x, kc = blockIdx.y, kbase = kc * 48;
  for (int i = threadIdx.x; i < 144; i += 128) {
    int d = i / 48, k = i - d * 48;
    float v;
    if (d == 0) {
      float acc = 0.f;
      for (int b = 0; b < 157; ++b)
        acc += ws[OFF_YPART + b * 6144 + h * 768 + kbase + k];
      v = acc * (1.0f / NN);
    } else {
      v = ws[OFF_Z + ((d - 1) * 8 + h) * 768 + kbase + k];
    }
    vL[i] = v;
  }
  __syncthreads();
  int c = threadIdx.x;
  float a0 = 0.f, a1 = 0.f, a2 = 0.f;
  #pragma unroll 4
  for (int k = 0; k < 48; ++k) {
    float wv = W[(kbase + k) * ODIM + h * 128 + c];
    a0 += vL[k] * wv;
    a1 += vL[48 + k] * wv;
    a2 += vL[96 + k] * wv;
  }
  int ib = h * 128 + c;
  float l0 = a0 * clf_W[2 * ib] + a1 * clf_W[2 * (1024 + ib)]
           + a2 * clf_W[2 * (2048 + ib)];
  float l1 = a0 * clf_W[2 * ib + 1] + a1 * clf_W[2 * (1024 + ib) + 1]
           + a2 * clf_W[2 * (2048 + ib) + 1];
  #pragma unroll
  for (int o = 32; o > 0; o >>= 1) {
    l0 += __shfl_down(l0, o, 64);
    l1 += __shfl_down(l1, o, 64);
  }
  if ((threadIdx.x & 63) == 0) {
    red[(threadIdx.x >> 6) * 2] = l0;
    red[(threadIdx.x >> 6) * 2 + 1] = l1;
  }
  __syncthreads();
  if (threadIdx.x == 0) {
    atomicAdd(&out[0], red[0] + red[2]);
    atomicAdd(&out[1], red[1] + red[3]);
  }
}

extern "C" void kernel_launch(void* const* d_in, const int* in_sizes, int n_in,
                              void* d_out, int out_size, void* d_ws, size_t ws_size,
                              hipStream_t stream) {
  const float* x        = (const float*)d_in[0];
  const int*   ei       = (const int*)d_in[1];
  const float* edge_attr= (const float*)d_in[2];
  const int*   tptr     = (const int*)d_in[3];
  const int*   iptr     = (const int*)d_in[4];
  const float* W        = (const float*)d_in[5];
  const float* att_src  = (const float*)d_in[6];
  const float* att_dst  = (const float*)d_in[7];
  const float* W_edge   = (const float*)d_in[8];
  const float* att_edge = (const float*)d_in[9];
  const float* bias     = (const float*)d_in[10];
  const float* clf_W    = (const float*)d_in[11];
  const float* clf_b    = (const float*)d_in[12];
  float* ws  = (float*)d_ws;
  float* out = (float*)d_out;

  hipMemsetAsync(ws + ZERO_START, 0, ZERO_CNT * sizeof(float), stream);
  k1f<<<755, 256, 0, stream>>>(W, att_src, att_dst, W_edge, att_edge, edge_attr, ei, ws);
  kAx<<<313, 256, 0, stream>>>(x, ws);
  kE<<<1330, 128, 0, stream>>>(ei, edge_attr, bias, clf_W, clf_b, out, ws);
  kD<<<625, 128, 0, stream>>>(ws);
  kSZ<<<637, 128, 0, stream>>>(x, tptr, iptr, ws);
  dim3 g7(157, 3);
  k7s<<<g7, 256, 0, stream>>>(x, ws);
  dim3 g8(8, 16);
  k8<<<g8, 128, 0, stream>>>(W, clf_W, out, ws);
}